// Round 12
// baseline (46.616 us; speedup 1.0000x reference)
//
#include <hip/hip_runtime.h>

#define NX 4096
#define NY 2048
#define NQ 1024         // float4 quads per row
#define EPS 1e-8f
#define INV_D 0.001f

typedef float f32x2 __attribute__((ext_vector_type(2)));
typedef float f32x4 __attribute__((ext_vector_type(4)));

__device__ __forceinline__ int clampi(int i, int lo, int hi) {
    return i < lo ? lo : (i > hi ? hi : i);
}

// Packed (2-wide) one-rcp WENO5: two independent faces at once.
__device__ __forceinline__ f32x2 weno5_pk(f32x2 qm2, f32x2 qm1, f32x2 q0,
                                          f32x2 qp1, f32x2 qp2) {
    f32x2 f1 = (1.0f/3.0f)*qm2 - (7.0f/6.0f)*qm1 + (11.0f/6.0f)*q0;
    f32x2 f2 = (-1.0f/6.0f)*qm1 + (5.0f/6.0f)*q0 + (1.0f/3.0f)*qp1;
    f32x2 f3 = (1.0f/3.0f)*q0 + (5.0f/6.0f)*qp1 - (1.0f/6.0f)*qp2;
    f32x2 d1 = qm2 - 2.0f*qm1 + q0;
    f32x2 e1 = qm2 - 4.0f*qm1 + 3.0f*q0;
    f32x2 d2 = qm1 - 2.0f*q0 + qp1;
    f32x2 e2 = qm1 - qp1;
    f32x2 d3 = q0 - 2.0f*qp1 + qp2;
    f32x2 e3 = 3.0f*q0 - 4.0f*qp1 + qp2;
    const float k1 = 13.0f/12.0f, k2 = 0.25f;
    f32x2 b1 = k1*(d1*d1) + k2*(e1*e1);
    f32x2 b2 = k1*(d2*d2) + k2*(e2*e2);
    f32x2 b3 = k1*(d3*d3) + k2*(e3*e3);
    f32x2 t1 = b1 + EPS, t2 = b2 + EPS, t3 = b3 + EPS;
    f32x2 p23 = t2*t3, p13 = t1*t3, p12 = t1*t2;
    f32x2 w1 = 0.1f*(p23*p23);
    f32x2 w2 = 0.6f*(p13*p13);
    f32x2 w3 = 0.3f*(p12*p12);
    f32x2 num = w1*f1 + w2*f2 + w3*f3;
    f32x2 den = (w1 + w2) + w3;
    f32x2 rc;
    rc.x = __builtin_amdgcn_rcpf(den.x);
    rc.y = __builtin_amdgcn_rcpf(den.y);
    return num * rc;
}

// One thread: 2 rows x 4 cols (one float4 quad). 29 VMEM / 512 cells per
// wave; 11 pk-WENO per thread with zero packing waste (fe packed across the
// row pair, fn packed across column pairs).
template <bool EDGE>
__device__ __forceinline__ void run_quad(const float* __restrict__ h,
                                         const float* __restrict__ u,
                                         const float* __restrict__ v,
                                         float* __restrict__ out,
                                         int q, int yA) {
    const int c0 = q * 4;
    const int yB = yA + 1;
    const f32x4* __restrict__ h4 = (const f32x4*)h;
    const f32x4* __restrict__ u4 = (const f32x4*)u;
    const f32x4* __restrict__ v4 = (const f32x4*)v;
    f32x4* __restrict__ out4 = (f32x4*)out;

    const int cm3 = EDGE ? clampi(c0 - 3, 0, NX - 1) : c0 - 3;
    const int cm2 = EDGE ? clampi(c0 - 2, 0, NX - 1) : c0 - 2;
    const int cm1 = EDGE ? clampi(c0 - 1, 0, NX - 1) : c0 - 1;
    const int cp4 = EDGE ? clampi(c0 + 4, 0, NX - 1) : c0 + 4;
    const int cp5 = EDGE ? clampi(c0 + 5, 0, NX - 1) : c0 + 5;
    const int cp6 = EDGE ? clampi(c0 + 6, 0, NX - 1) : c0 + 6;

    // ---- loads: 8 B-quads + 3 v-quads + 2 u-quads + 2 u-scalars + 12 halo
    f32x4 B[8];                          // h rows yA-3 .. yA+4, own quad
#pragma unroll
    for (int k = 0; k < 8; ++k) {
        int yy = EDGE ? clampi(yA - 3 + k, 0, NY - 1) : (yA - 3 + k);
        B[k] = h4[(size_t)yy * NQ + q];
    }
    f32x4 vq[3];                         // v rows yA-1, yA, yA+1
#pragma unroll
    for (int j = 0; j < 3; ++j) {
        int yy = EDGE ? clampi(yA - 1 + j, 0, NY - 1) : (yA - 1 + j);
        vq[j] = v4[(size_t)yy * NQ + q];
    }
    f32x4 uqA = u4[(size_t)yA * NQ + q];
    f32x4 uqB = u4[(size_t)yB * NQ + q];
    float umA = u[(size_t)yA * NX + cm1];
    float umB = u[(size_t)yB * NX + cm1];
    const float* hA = h + (size_t)yA * NX;
    const float* hB = h + (size_t)yB * NX;
    // x-stencils s[0..9] = h[row][c0-3 .. c0+6]
    float sA[10], sB[10];
    sA[0] = hA[cm3]; sA[1] = hA[cm2]; sA[2] = hA[cm1];
    sA[3] = B[3].x;  sA[4] = B[3].y;  sA[5] = B[3].z;  sA[6] = B[3].w;
    sA[7] = hA[cp4]; sA[8] = hA[cp5]; sA[9] = hA[cp6];
    sB[0] = hB[cm3]; sB[1] = hB[cm2]; sB[2] = hB[cm1];
    sB[3] = B[4].x;  sB[4] = B[4].y;  sB[5] = B[4].z;  sB[6] = B[4].w;
    sB[7] = hB[cp4]; sB[8] = hB[cp5]; sB[9] = hB[cp6];

    // ---- fn faces at rows yA-1, yA, yA+1 (vel v[row]); 2 pk per face row
    f32x4 fn[3];
#pragma unroll
    for (int k = 0; k < 3; ++k) {
        f32x4 vel = vq[k];
        bool sx = vel.x >= 0.0f, sy = vel.y >= 0.0f;
        bool sz = vel.z >= 0.0f, sw = vel.w >= 0.0f;
        f32x2 a = { sx ? B[k].x   : B[k+5].x, sy ? B[k].y   : B[k+5].y };
        f32x2 b = { sx ? B[k+1].x : B[k+4].x, sy ? B[k+1].y : B[k+4].y };
        f32x2 c = { sx ? B[k+2].x : B[k+3].x, sy ? B[k+2].y : B[k+3].y };
        f32x2 d = { sx ? B[k+3].x : B[k+2].x, sy ? B[k+3].y : B[k+2].y };
        f32x2 e = { sx ? B[k+4].x : B[k+1].x, sy ? B[k+4].y : B[k+1].y };
        f32x2 r1 = weno5_pk(a, b, c, d, e);
        a = { sz ? B[k].z   : B[k+5].z, sw ? B[k].w   : B[k+5].w };
        b = { sz ? B[k+1].z : B[k+4].z, sw ? B[k+1].w : B[k+4].w };
        c = { sz ? B[k+2].z : B[k+3].z, sw ? B[k+2].w : B[k+3].w };
        d = { sz ? B[k+3].z : B[k+2].z, sw ? B[k+3].w : B[k+2].w };
        e = { sz ? B[k+4].z : B[k+1].z, sw ? B[k+4].w : B[k+1].w };
        f32x2 r2 = weno5_pk(a, b, c, d, e);
        fn[k].x = vel.x * r1.x;  fn[k].y = vel.y * r1.y;
        fn[k].z = vel.z * r2.x;  fn[k].w = vel.w * r2.y;
    }

    // ---- fe faces at cols c0-1 .. c0+3, packed across the two rows
    float uvA[5] = { umA, uqA.x, uqA.y, uqA.z, uqA.w };
    float uvB[5] = { umB, uqB.x, uqB.y, uqB.z, uqB.w };
    float feA[5], feB[5];
#pragma unroll
    for (int f = 0; f < 5; ++f) {
        bool tA = uvA[f] >= 0.0f, tB = uvB[f] >= 0.0f;
        f32x2 a = { tA ? sA[f]   : sA[f+5], tB ? sB[f]   : sB[f+5] };
        f32x2 b = { tA ? sA[f+1] : sA[f+4], tB ? sB[f+1] : sB[f+4] };
        f32x2 c = { tA ? sA[f+2] : sA[f+3], tB ? sB[f+2] : sB[f+3] };
        f32x2 d = { tA ? sA[f+3] : sA[f+2], tB ? sB[f+3] : sB[f+2] };
        f32x2 e = { tA ? sA[f+4] : sA[f+1], tB ? sB[f+4] : sB[f+1] };
        f32x2 r = weno5_pk(a, b, c, d, e);
        feA[f] = uvA[f] * r.x;
        feB[f] = uvB[f] * r.y;
    }

    // ---- combine: out[y][c] = ((fe[c-1]-fe[c]) + (fn[y-1]-fn[y])) / D
    f32x4 valA, valB;
    valA.x = ((feA[0] - feA[1]) + (fn[0].x - fn[1].x)) * INV_D;
    valA.y = ((feA[1] - feA[2]) + (fn[0].y - fn[1].y)) * INV_D;
    valA.z = ((feA[2] - feA[3]) + (fn[0].z - fn[1].z)) * INV_D;
    valA.w = ((feA[3] - feA[4]) + (fn[0].w - fn[1].w)) * INV_D;
    valB.x = ((feB[0] - feB[1]) + (fn[1].x - fn[2].x)) * INV_D;
    valB.y = ((feB[1] - feB[2]) + (fn[1].y - fn[2].y)) * INV_D;
    valB.z = ((feB[2] - feB[3]) + (fn[1].z - fn[2].z)) * INV_D;
    valB.w = ((feB[3] - feB[4]) + (fn[1].w - fn[2].w)) * INV_D;

    if (EDGE) {
        bool okA = (yA >= 2) && (yA < NY - 2);
        bool okB = (yB >= 2) && (yB < NY - 2);
        bool glo = (q == 0);        // cols c0, c0+1 are ghost
        bool ghi = (q == NQ - 1);   // cols c0+2, c0+3 are ghost
        valA.x = (okA && !glo) ? valA.x : 0.0f;
        valA.y = (okA && !glo) ? valA.y : 0.0f;
        valA.z = (okA && !ghi) ? valA.z : 0.0f;
        valA.w = (okA && !ghi) ? valA.w : 0.0f;
        valB.x = (okB && !glo) ? valB.x : 0.0f;
        valB.y = (okB && !glo) ? valB.y : 0.0f;
        valB.z = (okB && !ghi) ? valB.z : 0.0f;
        valB.w = (okB && !ghi) ? valB.w : 0.0f;
    }
    __builtin_nontemporal_store(valA, &out4[(size_t)yA * NQ + q]);
    __builtin_nontemporal_store(valB, &out4[(size_t)yB * NQ + q]);
}

__global__ __launch_bounds__(256, 5) void adv_kernel(const float* __restrict__ h,
                                                     const float* __restrict__ u,
                                                     const float* __restrict__ v,
                                                     float* __restrict__ out) {
    const int lane = threadIdx.x & 63;
    const int wid  = threadIdx.x >> 6;
    const int q  = blockIdx.x * 64 + lane;      // quad 0..1023
    const int yA = blockIdx.y * 8 + wid * 2;    // 2 rows per thread

    const bool edge = (blockIdx.x == 0) || (blockIdx.x == gridDim.x - 1) ||
                      (blockIdx.y == 0) || (blockIdx.y == gridDim.y - 1);
    if (edge)
        run_quad<true>(h, u, v, out, q, yA);
    else
        run_quad<false>(h, u, v, out, q, yA);
}

extern "C" void kernel_launch(void* const* d_in, const int* in_sizes, int n_in,
                              void* d_out, int out_size, void* d_ws, size_t ws_size,
                              hipStream_t stream) {
    const float* h = (const float*)d_in[0];
    const float* u = (const float*)d_in[1];
    const float* v = (const float*)d_in[2];
    float* out = (float*)d_out;

    dim3 block(256, 1, 1);
    dim3 grid(NQ / 64, NY / 8, 1);   // 16 x 256 = 4096 blocks
    adv_kernel<<<grid, block, 0, stream>>>(h, u, v, out);
}

// Round 13
// 40.581 us; speedup vs baseline: 1.1487x; 1.1487x over previous
//
#include <hip/hip_runtime.h>

#define NX 4096
#define NY 2048
#define EPS 1e-8f
#define ROWS 8          // rows per wave strip
#define CPW 56          // output columns per block (stencil stays in-wave)
#define INV_D 0.001f

typedef float f32x2 __attribute__((ext_vector_type(2)));

__device__ __forceinline__ int clampi(int i, int lo, int hi) {
    return i < lo ? lo : (i > hi ? hi : i);
}

// Scalar one-rcp WENO5 (leading fn face only).
__device__ __forceinline__ float weno5_s(float qm2, float qm1, float q0,
                                         float qp1, float qp2) {
    float f1 = fmaf(1.0f/3.0f, qm2, fmaf(-7.0f/6.0f, qm1, (11.0f/6.0f)*q0));
    float f2 = fmaf(-1.0f/6.0f, qm1, fmaf(5.0f/6.0f, q0, (1.0f/3.0f)*qp1));
    float f3 = fmaf(1.0f/3.0f, q0, fmaf(5.0f/6.0f, qp1, (-1.0f/6.0f)*qp2));
    const float k1 = 13.0f/12.0f, k2 = 0.25f;
    float d1 = qm2 - 2.0f*qm1 + q0,  e1 = qm2 - 4.0f*qm1 + 3.0f*q0;
    float d2 = qm1 - 2.0f*q0 + qp1,  e2 = qm1 - qp1;
    float d3 = q0 - 2.0f*qp1 + qp2,  e3 = 3.0f*q0 - 4.0f*qp1 + qp2;
    float b1 = fmaf(k1, d1*d1, k2*(e1*e1));
    float b2 = fmaf(k1, d2*d2, k2*(e2*e2));
    float b3 = fmaf(k1, d3*d3, k2*(e3*e3));
    float t1 = b1 + EPS, t2 = b2 + EPS, t3 = b3 + EPS;
    float p23 = t2*t3, p13 = t1*t3, p12 = t1*t2;
    float w1 = 0.1f*(p23*p23), w2 = 0.6f*(p13*p13), w3 = 0.3f*(p12*p12);
    float num = fmaf(w1, f1, fmaf(w2, f2, w3*f3));
    return num * __builtin_amdgcn_rcpf((w1 + w2) + w3);
}

// Packed (2-wide) one-rcp WENO5: .x = fe face, .y = fn face.
__device__ __forceinline__ f32x2 weno5_pk(f32x2 qm2, f32x2 qm1, f32x2 q0,
                                          f32x2 qp1, f32x2 qp2) {
    f32x2 f1 = (1.0f/3.0f)*qm2 - (7.0f/6.0f)*qm1 + (11.0f/6.0f)*q0;
    f32x2 f2 = (-1.0f/6.0f)*qm1 + (5.0f/6.0f)*q0 + (1.0f/3.0f)*qp1;
    f32x2 f3 = (1.0f/3.0f)*q0 + (5.0f/6.0f)*qp1 - (1.0f/6.0f)*qp2;
    f32x2 d1 = qm2 - 2.0f*qm1 + q0;
    f32x2 e1 = qm2 - 4.0f*qm1 + 3.0f*q0;
    f32x2 d2 = qm1 - 2.0f*q0 + qp1;
    f32x2 e2 = qm1 - qp1;
    f32x2 d3 = q0 - 2.0f*qp1 + qp2;
    f32x2 e3 = 3.0f*q0 - 4.0f*qp1 + qp2;
    const float k1 = 13.0f/12.0f, k2 = 0.25f;
    f32x2 b1 = k1*(d1*d1) + k2*(e1*e1);
    f32x2 b2 = k1*(d2*d2) + k2*(e2*e2);
    f32x2 b3 = k1*(d3*d3) + k2*(e3*e3);
    f32x2 t1 = b1 + EPS, t2 = b2 + EPS, t3 = b3 + EPS;
    f32x2 p23 = t2*t3, p13 = t1*t3, p12 = t1*t2;
    f32x2 w1 = 0.1f*(p23*p23);
    f32x2 w2 = 0.6f*(p13*p13);
    f32x2 w3 = 0.3f*(p12*p12);
    f32x2 num = w1*f1 + w2*f2 + w3*f3;
    f32x2 den = (w1 + w2) + w3;
    f32x2 rc;
    rc.x = __builtin_amdgcn_rcpf(den.x);
    rc.y = __builtin_amdgcn_rcpf(den.y);
    return num * rc;
}

// ---------------- interior strip: shfl-stencil, 39 VMEM / 448 cells -------
__device__ __forceinline__ void run_int(const float* __restrict__ h,
                                        const float* __restrict__ u,
                                        const float* __restrict__ v,
                                        float* __restrict__ out,
                                        int x0, int y0w, int lane) {
    const int xh = x0 - 3 + lane;    // h row-load column (covers all stencils)
    const int xq = x0 - 1 + lane;    // face column (u load)
    const int xc = x0 + lane;        // output / v / column-stencil column

    // ---- batched loads: 8 hv + 6 col head/tail + 8 u + 9 v = 31 VMEM ----
    float hv[ROWS];
#pragma unroll
    for (int r = 0; r < ROWS; ++r)
        hv[r] = h[(size_t)(y0w + r) * NX + xh];
    float col[ROWS + 6];
#pragma unroll
    for (int k = 0; k < 3; ++k) {
        col[k] = h[(size_t)(y0w - 3 + k) * NX + xc];
        col[ROWS + 3 + k] = h[(size_t)(y0w + ROWS + k) * NX + xc];
    }
    float uu[ROWS];
#pragma unroll
    for (int r = 0; r < ROWS; ++r)
        uu[r] = u[(size_t)(y0w + r) * NX + xq];
    float vv[ROWS + 1];
#pragma unroll
    for (int j = 0; j <= ROWS; ++j)
        vv[j] = v[(size_t)(y0w - 1 + j) * NX + xc];

    // column mids come from the row loads via one shuffle each
#pragma unroll
    for (int r = 0; r < ROWS; ++r)
        col[3 + r] = __shfl(hv[r], lane + 3);

    // ---- compute (identical structure to the proven R5 phase 2) ----
    float fn_prev;
    {
        float vl = vv[0];
        bool vp = (vl >= 0.0f);
        fn_prev = vl * weno5_s(vp ? col[0] : col[5], vp ? col[1] : col[4],
                               vp ? col[2] : col[3], vp ? col[3] : col[2],
                               vp ? col[4] : col[1]);
    }

#pragma unroll
    for (int r = 0; r < ROWS; ++r) {
        const int y = y0w + r;
        // 6-point x-stencil from wave shuffles (s3 shared with col)
        float s0 = hv[r];
        float s1 = __shfl(hv[r], lane + 1);
        float s2 = __shfl(hv[r], lane + 2);
        float s3 = col[r + 3];
        float s4 = __shfl(hv[r], lane + 4);
        float s5 = __shfl(hv[r], lane + 5);

        float uval = uu[r];
        float vval = vv[r + 1];
        bool up = (uval >= 0.0f);
        bool vp = (vval >= 0.0f);
        f32x2 a = { up ? s0 : s5, vp ? col[r+1] : col[r+6] };
        f32x2 b = { up ? s1 : s4, vp ? col[r+2] : col[r+5] };
        f32x2 c = { up ? s2 : s3, vp ? col[r+3] : col[r+4] };
        f32x2 d = { up ? s3 : s2, vp ? col[r+4] : col[r+3] };
        f32x2 e = { up ? s4 : s1, vp ? col[r+5] : col[r+2] };
        f32x2 q = weno5_pk(a, b, c, d, e);
        float fe = uval * q.x;            // face at column xc-1
        float fn_cur = vval * q.y;        // face at row y
        float fe_r = __shfl_down(fe, 1);  // face at column xc
        float val = ((fe - fe_r) + (fn_prev - fn_cur)) * INV_D;  // = -div

        if (lane < CPW)
            __builtin_nontemporal_store(val, out + (size_t)y * NX + xc);
        fn_prev = fn_cur;
    }
}

// ---------------- edge strip: R5's clamped scalar-load path ---------------
__device__ __forceinline__ void run_edge(const float* __restrict__ h,
                                         const float* __restrict__ u,
                                         const float* __restrict__ v,
                                         float* __restrict__ out,
                                         int x0, int y0w, int lane) {
    const int xf = x0 - 1 + lane;
    const int xo = x0 + lane;
    const int xc = xo < NX ? xo : NX - 1;
    const int xq = clampi(xf, 0, NX - 1);

    int xs[6];
#pragma unroll
    for (int k = 0; k < 6; ++k) xs[k] = clampi(xf - 2 + k, 0, NX - 1);

    float col[ROWS + 6];
#pragma unroll
    for (int k = 0; k < ROWS + 6; ++k) {
        int yy = clampi(y0w - 3 + k, 0, NY - 1);
        col[k] = h[(size_t)yy * NX + xc];
    }
    float vv[ROWS + 1];
#pragma unroll
    for (int j = 0; j <= ROWS; ++j) {
        int fy = clampi(y0w - 1 + j, 0, NY - 1);
        vv[j] = v[(size_t)fy * NX + xc];
    }
    float uu[ROWS];
#pragma unroll
    for (int r = 0; r < ROWS; ++r)
        uu[r] = u[(size_t)(y0w + r) * NX + xq];
    float st[ROWS][6];
#pragma unroll
    for (int r = 0; r < ROWS; ++r) {
        const float* hr = h + (size_t)(y0w + r) * NX;
#pragma unroll
        for (int k = 0; k < 6; ++k) st[r][k] = hr[xs[k]];
    }

    float fn_prev;
    {
        float vl = vv[0];
        bool vp = (vl >= 0.0f);
        fn_prev = vl * weno5_s(vp ? col[0] : col[5], vp ? col[1] : col[4],
                               vp ? col[2] : col[3], vp ? col[3] : col[2],
                               vp ? col[4] : col[1]);
    }

#pragma unroll
    for (int r = 0; r < ROWS; ++r) {
        const int y = y0w + r;
        float uval = uu[r];
        float vval = vv[r + 1];
        bool up = (uval >= 0.0f);
        bool vp = (vval >= 0.0f);
        f32x2 a = { up ? st[r][0] : st[r][5], vp ? col[r+1] : col[r+6] };
        f32x2 b = { up ? st[r][1] : st[r][4], vp ? col[r+2] : col[r+5] };
        f32x2 c = { up ? st[r][2] : st[r][3], vp ? col[r+3] : col[r+4] };
        f32x2 d = { up ? st[r][3] : st[r][2], vp ? col[r+4] : col[r+3] };
        f32x2 e = { up ? st[r][4] : st[r][1], vp ? col[r+5] : col[r+2] };
        f32x2 q = weno5_pk(a, b, c, d, e);
        float fe = uval * q.x;
        float fn_cur = vval * q.y;
        float fe_r = __shfl_down(fe, 1);
        float val = 0.0f;
        if (xo >= 2 && xo < NX - 2 && y >= 2 && y < NY - 2)
            val = ((fe - fe_r) + (fn_prev - fn_cur)) * INV_D;
        if (lane < CPW && xo < NX)
            __builtin_nontemporal_store(val, out + (size_t)y * NX + xo);
        fn_prev = fn_cur;
    }
}

__global__ __launch_bounds__(256) void adv_kernel(const float* __restrict__ h,
                                                  const float* __restrict__ u,
                                                  const float* __restrict__ v,
                                                  float* __restrict__ out) {
    const int lane = threadIdx.x & 63;
    const int wid  = threadIdx.x >> 6;
    const int x0 = blockIdx.x * CPW;
    const int y0w = (blockIdx.y * 4 + wid) * ROWS;

    // interior needs x0-3 >= 0 and x0+60 <= NX-1, plus full y halo in-range
    const bool edge = (blockIdx.x == 0) || (blockIdx.x >= (NX / CPW)) ||
                      (blockIdx.y == 0) || (blockIdx.y == gridDim.y - 1);
    if (edge)
        run_edge(h, u, v, out, x0, y0w, lane);
    else
        run_int(h, u, v, out, x0, y0w, lane);
}

extern "C" void kernel_launch(void* const* d_in, const int* in_sizes, int n_in,
                              void* d_out, int out_size, void* d_ws, size_t ws_size,
                              hipStream_t stream) {
    const float* h = (const float*)d_in[0];
    const float* u = (const float*)d_in[1];
    const float* v = (const float*)d_in[2];
    float* out = (float*)d_out;

    dim3 block(256, 1, 1);
    dim3 grid((NX + CPW - 1) / CPW, NY / (4 * ROWS), 1);  // 74 x 64
    adv_kernel<<<grid, block, 0, stream>>>(h, u, v, out);
}